// Round 2
// baseline (16916.042 us; speedup 1.0000x reference)
//
#include <hip/hip_runtime.h>
#include <hip/hip_fp16.h>

#define LDIM 200
#define BDIM 512
#define IDIM 512
#define HDIM 512
#define GDIM 1536  // 3*H

typedef _Float16 f16x8 __attribute__((ext_vector_type(8)));
typedef float    f32x4 __attribute__((ext_vector_type(4)));

// ---------------------------------------------------------------------------
// K0: pack w_hh (f32 [1536][512]) into MFMA B-fragment order, f16.
// unit u = (ntg*16 + kk)*64 + lane   (one f16x8 = 16B per unit)
// element j of unit u:  n = ntg*16 + (lane&15),  k = kk*32 + (lane>>4)*8 + j
// ---------------------------------------------------------------------------
__global__ __launch_bounds__(256) void k_pack_wf(
    const float* __restrict__ w, f16x8* __restrict__ wf)
{
    int u = blockIdx.x * 256 + threadIdx.x;      // 96*16*64 = 98304 units
    if (u >= (GDIM / 16) * 16 * 64) return;
    const int lane = u & 63;
    const int kk   = (u >> 6) & 15;
    const int ntg  = u >> 10;
    const int n = ntg * 16 + (lane & 15);
    const int k = kk * 32 + (lane >> 4) * 8;
    const float* src = w + (size_t)n * HDIM + k;
    f16x8 v;
    #pragma unroll
    for (int j = 0; j < 8; ++j) v[j] = (_Float16)src[j];
    wf[u] = v;
}

// ---------------------------------------------------------------------------
// K1: gx[m][n] = x_row(m) . w_ih[n][:] + b_ih[n],  m = l*512 + b, stored f16.
// No LDS: A and B loaded f32 from global (L2-resident via XCD swizzle),
// converted in-register, MFMA 16x16x32_f16.  Block = 128x128 tile, 4 waves,
// wave w owns m-rows [w*32, w*32+32) x all 128 n.
// Grid 9600 blocks 1D, XCD-chunked: xcd = bid&7 owns m-groups [xcd*100,+100).
// ---------------------------------------------------------------------------
__global__ __launch_bounds__(256) void k_gemm_gx(
    const float* __restrict__ x, const float* __restrict__ wih,
    const float* __restrict__ bih, _Float16* __restrict__ gx)
{
    const int bid  = blockIdx.x;
    const int xcd  = bid & 7;
    const int slot = bid >> 3;                   // 0..1199
    const int gl   = slot / 12;                  // local m-group 0..99
    const int j    = slot - gl * 12;             // n-group 0..11
    const int m0   = (xcd * 100 + gl) * 128;
    const int n0   = j * 128;

    const int t = threadIdx.x;
    const int w = t >> 6;
    const int l = t & 63;
    const int mw = m0 + w * 32;
    const int ko = (l >> 4) * 8;                 // k offset within 32-chunk

    // A row pointers (x is [b][l][k], m = l*512 + b)
    const int r0 = mw + (l & 15);
    const int r1 = r0 + 16;
    const float* a0 = x + ((size_t)(r0 & 511) * LDIM + (r0 >> 9)) * IDIM;
    const float* a1 = x + ((size_t)(r1 & 511) * LDIM + (r1 >> 9)) * IDIM;
    // B row pointers: n = n0 + nt*16 + (l&15)
    const float* bp = wih + (size_t)(n0 + (l & 15)) * IDIM;

    f32x4 acc[2][8] = {};

    for (int kk = 0; kk < 16; ++kk) {
        const int k = kk * 32 + ko;
        f16x8 af[2];
        {
            const float4 v0 = *reinterpret_cast<const float4*>(a0 + k);
            const float4 v1 = *reinterpret_cast<const float4*>(a0 + k + 4);
            const float4 v2 = *reinterpret_cast<const float4*>(a1 + k);
            const float4 v3 = *reinterpret_cast<const float4*>(a1 + k + 4);
            af[0][0] = (_Float16)v0.x; af[0][1] = (_Float16)v0.y;
            af[0][2] = (_Float16)v0.z; af[0][3] = (_Float16)v0.w;
            af[0][4] = (_Float16)v1.x; af[0][5] = (_Float16)v1.y;
            af[0][6] = (_Float16)v1.z; af[0][7] = (_Float16)v1.w;
            af[1][0] = (_Float16)v2.x; af[1][1] = (_Float16)v2.y;
            af[1][2] = (_Float16)v2.z; af[1][3] = (_Float16)v2.w;
            af[1][4] = (_Float16)v3.x; af[1][5] = (_Float16)v3.y;
            af[1][6] = (_Float16)v3.z; af[1][7] = (_Float16)v3.w;
        }
        #pragma unroll
        for (int nt = 0; nt < 8; ++nt) {
            const float* br = bp + (size_t)nt * 16 * IDIM + k;
            const float4 v0 = *reinterpret_cast<const float4*>(br);
            const float4 v1 = *reinterpret_cast<const float4*>(br + 4);
            f16x8 bf;
            bf[0] = (_Float16)v0.x; bf[1] = (_Float16)v0.y;
            bf[2] = (_Float16)v0.z; bf[3] = (_Float16)v0.w;
            bf[4] = (_Float16)v1.x; bf[5] = (_Float16)v1.y;
            bf[6] = (_Float16)v1.z; bf[7] = (_Float16)v1.w;
            acc[0][nt] = __builtin_amdgcn_mfma_f32_16x16x32_f16(af[0], bf, acc[0][nt], 0, 0, 0);
            acc[1][nt] = __builtin_amdgcn_mfma_f32_16x16x32_f16(af[1], bf, acc[1][nt], 0, 0, 0);
        }
    }

    // Epilogue: D layout col = lane&15, row = (lane>>4)*4 + reg
    #pragma unroll
    for (int nt = 0; nt < 8; ++nt) {
        const int n = n0 + nt * 16 + (l & 15);
        const float bv = bih[n];
        #pragma unroll
        for (int mt = 0; mt < 2; ++mt) {
            #pragma unroll
            for (int r = 0; r < 4; ++r) {
                const int m = mw + mt * 16 + (l >> 4) * 4 + r;
                gx[(size_t)m * GDIM + n] = (_Float16)(acc[mt][nt][r] + bv);
            }
        }
    }
}

// ---------------------------------------------------------------------------
// K2: recurrence.  256 blocks x 2 batch rows, 512 threads (8 waves).
// Phase 1: gh = h @ w_hh^T via MFMA; wave w owns cols [w*192, w*192+192).
//   A-frags from LDS h16 (rows duplicated via l&1; D rows 2..15 discarded).
//   B-frags stream from fragment-packed wf (coalesced 1KB per wave-load).
// Phase 2: thread t owns h column t (gates t, t+512, t+1024), as round-0.
// ---------------------------------------------------------------------------
__global__ __launch_bounds__(512, 2) void k_recur(
    const _Float16* __restrict__ gx, const float* __restrict__ att,
    const float* __restrict__ h0, const f16x8* __restrict__ wf,
    const float* __restrict__ bhh, float* __restrict__ out,
    float* __restrict__ hx)
{
    const int b0 = blockIdx.x << 1;
    const int t  = threadIdx.x;
    const int w  = t >> 6;
    const int l  = t & 63;

    __shared__ float hsh[2][HDIM];
    __shared__ __align__(16) _Float16 h16[2][HDIM];
    __shared__ float ghs[2][GDIM];
    __shared__ float atts[2][LDIM];

    {
        const float v0 = h0[(size_t)b0 * HDIM + t];
        const float v1 = h0[(size_t)(b0 + 1) * HDIM + t];
        hsh[0][t] = v0; hsh[1][t] = v1;
        h16[0][t] = (_Float16)v0; h16[1][t] = (_Float16)v1;
        if (t < LDIM) {
            atts[0][t] = att[(size_t)t * BDIM + b0];
            atts[1][t] = att[(size_t)t * BDIM + b0 + 1];
        }
    }
    const float bh_r = bhh[t];
    const float bh_z = bhh[t + 512];
    const float bh_n = bhh[t + 1024];

    const int arow = l & 1;                      // duplicate h rows across A
    const int ko   = (l >> 4) * 8;
    const f16x8* wfw = wf + (size_t)(w * 12) * 1024 + l;  // ntg stride 1024 units

    __syncthreads();

    for (int step = 0; step < LDIM; ++step) {
        // prefetch gx gates for phase 2 (independent of h)
        const _Float16* gxr0 = gx + ((size_t)step * BDIM + b0) * GDIM;
        const _Float16* gxr1 = gxr0 + GDIM;
        const float xr0 = (float)gxr0[t];
        const float xz0 = (float)gxr0[t + 512];
        const float xn0 = (float)gxr0[t + 1024];
        const float xr1 = (float)gxr1[t];
        const float xz1 = (float)gxr1[t + 512];
        const float xn1 = (float)gxr1[t + 1024];

        // hoist all A-fragments (h row, 8 contiguous f16 per lane per kk)
        f16x8 a[16];
        #pragma unroll
        for (int kk = 0; kk < 16; ++kk)
            a[kk] = *reinterpret_cast<const f16x8*>(&h16[arow][kk * 32 + ko]);

        // MFMA: 12 n-tiles x 16 k-steps
        const f16x8* wpn = wfw;
        for (int nt = 0; nt < 12; ++nt) {
            f32x4 acc = {0.f, 0.f, 0.f, 0.f};
            #pragma unroll
            for (int kk = 0; kk < 16; ++kk)
                acc = __builtin_amdgcn_mfma_f32_16x16x32_f16(a[kk], wpn[kk * 64], acc, 0, 0, 0);
            wpn += 1024;
            if (l < 16) {                        // rows 0,1 live in regs 0,1 of lanes 0-15
                const int col = (w * 12 + nt) * 16 + l;
                ghs[0][col] = acc[0];
                ghs[1][col] = acc[1];
            }
        }
        __syncthreads();

        // phase 2: gates + h update; thread t owns h column t
        {
            const float hr = ghs[0][t] + bh_r;
            const float hz = ghs[0][t + 512] + bh_z;
            const float hn = ghs[0][t + 1024] + bh_n;
            const float h  = hsh[0][t];
            const float rg = 1.f / (1.f + __expf(-(xr0 + hr)));
            const float zg = 1.f / (1.f + __expf(-(xz0 + hz)));
            const float ng = tanhf(xn0 + rg * hn);
            const float ho = (1.f - zg) * ng + zg * h;
            const float wv = atts[0][step];
            const float hnew = (1.f - wv) * h + wv * ho;
            hsh[0][t] = hnew; h16[0][t] = (_Float16)hnew;
            out[((size_t)b0 * LDIM + step) * HDIM + t] = hnew;
        }
        {
            const float hr = ghs[1][t] + bh_r;
            const float hz = ghs[1][t + 512] + bh_z;
            const float hn = ghs[1][t + 1024] + bh_n;
            const float h  = hsh[1][t];
            const float rg = 1.f / (1.f + __expf(-(xr1 + hr)));
            const float zg = 1.f / (1.f + __expf(-(xz1 + hz)));
            const float ng = tanhf(xn1 + rg * hn);
            const float ho = (1.f - zg) * ng + zg * h;
            const float wv = atts[1][step];
            const float hnew = (1.f - wv) * h + wv * ho;
            hsh[1][t] = hnew; h16[1][t] = (_Float16)hnew;
            out[((size_t)(b0 + 1) * LDIM + step) * HDIM + t] = hnew;
        }
        __syncthreads();
    }

    hx[(size_t)b0 * HDIM + t]       = hsh[0][t];
    hx[(size_t)(b0 + 1) * HDIM + t] = hsh[1][t];
}

// ---------------------------------------------------------------------------
extern "C" void kernel_launch(void* const* d_in, const int* in_sizes, int n_in,
                              void* d_out, int out_size, void* d_ws, size_t ws_size,
                              hipStream_t stream)
{
    const float* x   = (const float*)d_in[0];
    const float* att = (const float*)d_in[1];
    const float* h0  = (const float*)d_in[2];
    const float* wih = (const float*)d_in[3];
    const float* whh = (const float*)d_in[4];
    const float* bih = (const float*)d_in[5];
    const float* bhh = (const float*)d_in[6];

    float* out = (float*)d_out;
    float* hx  = out + (size_t)BDIM * LDIM * HDIM;

    // ws layout: [0, 1.5MB) wf (fragment-packed w_hh f16) ; [2MB, +315MB) gx f16
    f16x8*    wf = (f16x8*)d_ws;
    _Float16* gx = (_Float16*)((char*)d_ws + ((size_t)2 << 20));

    k_pack_wf<<<384, 256, 0, stream>>>(whh, wf);
    k_gemm_gx<<<9600, 256, 0, stream>>>(x, wih, bih, gx);
    k_recur<<<BDIM / 2, 512, 0, stream>>>(gx, att, h0, wf, bhh, out, hx);
}

// Round 3
// 3784.890 us; speedup vs baseline: 4.4694x; 4.4694x over previous
//
#include <hip/hip_runtime.h>
#include <hip/hip_fp16.h>

#define LDIM 200
#define BDIM 512
#define IDIM 512
#define HDIM 512
#define GDIM 1536  // 3*H
#define NGRP 16    // batch groups (32 rows each)
#define NCOL 16    // col groups   (32 h-cols each)

typedef _Float16 f16x8 __attribute__((ext_vector_type(8)));
typedef float    f32x4 __attribute__((ext_vector_type(4)));

// ---------------------------------------------------------------------------
// k_init: zero per-(group,step) barrier counters; convert h0 -> hb[0] (f16)
// ---------------------------------------------------------------------------
__global__ __launch_bounds__(256) void k_init(
    unsigned int* __restrict__ ctr, const float* __restrict__ h0,
    _Float16* __restrict__ hb)
{
    int i = blockIdx.x * 256 + threadIdx.x;      // grid covers 512*512
    if (i < NGRP * LDIM) ctr[i] = 0;
    if (i < BDIM * HDIM) hb[i] = (_Float16)h0[i];
}

// ---------------------------------------------------------------------------
// k_pack_wfi: pack w_ih (f32 [1536][512]) into MFMA B-fragment order, f16.
// unit u = (ntg*16 + kk)*64 + lane ;  n = ntg*16+(lane&15), k = kk*32+(lane>>4)*8+j
// (identical to round-2 k_pack_wf, which is correctness-verified)
// ---------------------------------------------------------------------------
__global__ __launch_bounds__(256) void k_pack_wfi(
    const float* __restrict__ w, f16x8* __restrict__ wf)
{
    int u = blockIdx.x * 256 + threadIdx.x;      // 96*16*64 = 98304 units
    if (u >= (GDIM / 16) * 16 * 64) return;
    const int lane = u & 63;
    const int kk   = (u >> 6) & 15;
    const int ntg  = u >> 10;
    const int n = ntg * 16 + (lane & 15);
    const int k = kk * 32 + (lane >> 4) * 8;
    const float* src = w + (size_t)n * IDIM + k;
    f16x8 v;
    #pragma unroll
    for (int j = 0; j < 8; ++j) v[j] = (_Float16)src[j];
    wf[u] = v;
}

// ---------------------------------------------------------------------------
// k_pack_wfh: pack w_hh into per-colgroup fragment order.
// u = ((c*6 + wv)*16 + kk)*64 + lane ; n_local = wv*16+(lane&15) in [0,96):
//   gate = n_local>>5, j_local = n_local&31, n_global = gate*512 + c*32 + j_local
// ---------------------------------------------------------------------------
__global__ __launch_bounds__(256) void k_pack_wfh(
    const float* __restrict__ w, f16x8* __restrict__ wf)
{
    int u = blockIdx.x * 256 + threadIdx.x;      // 16*6*16*64 = 98304 units
    if (u >= NCOL * 6 * 16 * 64) return;
    const int lane = u & 63;
    const int kk   = (u >> 6) & 15;
    const int cw   = u >> 10;                    // c*6 + wv
    const int wv   = cw % 6;
    const int c    = cw / 6;
    const int n_local = wv * 16 + (lane & 15);
    const int gate    = n_local >> 5;
    const int j_local = n_local & 31;
    const int n = gate * 512 + c * 32 + j_local;
    const int k = kk * 32 + (lane >> 4) * 8;
    const float* src = w + (size_t)n * HDIM + k;
    f16x8 v;
    #pragma unroll
    for (int j = 0; j < 8; ++j) v[j] = (_Float16)src[j];
    wf[u] = v;
}

// ---------------------------------------------------------------------------
// K1: gx = x @ w_ih^T + b_ih (f16 out).  Round-2-verified structure; B now
// loaded from fragment-packed f16 (zero B-side cvts).
// ---------------------------------------------------------------------------
__global__ __launch_bounds__(256) void k_gemm_gx(
    const float* __restrict__ x, const f16x8* __restrict__ wfi,
    const float* __restrict__ bih, _Float16* __restrict__ gx)
{
    const int bid  = blockIdx.x;
    const int xcd  = bid & 7;
    const int slot = bid >> 3;
    const int gl   = slot / 12;
    const int j    = slot - gl * 12;
    const int m0   = (xcd * 100 + gl) * 128;
    const int n0   = j * 128;

    const int t = threadIdx.x;
    const int w = t >> 6;
    const int l = t & 63;
    const int mw = m0 + w * 32;
    const int ko = (l >> 4) * 8;

    const int r0 = mw + (l & 15);
    const int r1 = r0 + 16;
    const float* a0 = x + ((size_t)(r0 & 511) * LDIM + (r0 >> 9)) * IDIM;
    const float* a1 = x + ((size_t)(r1 & 511) * LDIM + (r1 >> 9)) * IDIM;
    const f16x8* bp = wfi + (size_t)(j * 8) * 1024 + l;

    f32x4 acc[2][8] = {};

    for (int kk = 0; kk < 16; ++kk) {
        const int k = kk * 32 + ko;
        f16x8 af[2];
        {
            const float4 v0 = *reinterpret_cast<const float4*>(a0 + k);
            const float4 v1 = *reinterpret_cast<const float4*>(a0 + k + 4);
            const float4 v2 = *reinterpret_cast<const float4*>(a1 + k);
            const float4 v3 = *reinterpret_cast<const float4*>(a1 + k + 4);
            af[0][0] = (_Float16)v0.x; af[0][1] = (_Float16)v0.y;
            af[0][2] = (_Float16)v0.z; af[0][3] = (_Float16)v0.w;
            af[0][4] = (_Float16)v1.x; af[0][5] = (_Float16)v1.y;
            af[0][6] = (_Float16)v1.z; af[0][7] = (_Float16)v1.w;
            af[1][0] = (_Float16)v2.x; af[1][1] = (_Float16)v2.y;
            af[1][2] = (_Float16)v2.z; af[1][3] = (_Float16)v2.w;
            af[1][4] = (_Float16)v3.x; af[1][5] = (_Float16)v3.y;
            af[1][6] = (_Float16)v3.z; af[1][7] = (_Float16)v3.w;
        }
        const f16x8* bk = bp + kk * 64;
        #pragma unroll
        for (int nt = 0; nt < 8; ++nt) {
            const f16x8 bf = bk[(size_t)nt * 1024];
            acc[0][nt] = __builtin_amdgcn_mfma_f32_16x16x32_f16(af[0], bf, acc[0][nt], 0, 0, 0);
            acc[1][nt] = __builtin_amdgcn_mfma_f32_16x16x32_f16(af[1], bf, acc[1][nt], 0, 0, 0);
        }
    }

    #pragma unroll
    for (int nt = 0; nt < 8; ++nt) {
        const int n = n0 + nt * 16 + (l & 15);
        const float bv = bih[n];
        #pragma unroll
        for (int mt = 0; mt < 2; ++mt) {
            #pragma unroll
            for (int r = 0; r < 4; ++r) {
                const int m = mw + mt * 16 + (l >> 4) * 4 + r;
                gx[(size_t)m * GDIM + n] = (_Float16)(acc[mt][nt][r] + bv);
            }
        }
    }
}

// ---------------------------------------------------------------------------
// K2: persistent recurrence. 256 blocks = 16 batch-groups x 16 col-groups,
// 384 threads (6 waves). Block (g,c) owns rows g*32..+32, h-cols c*32..+32.
// w_hh slice lives in REGISTERS (wave w: 16 B-frags = 64 VGPR). Per step:
// stage h (f16, XOR-swizzled LDS) -> MFMA -> gates (h_old kept locally f32)
// -> write 2KB h-patch -> per-group 16-block agent-scope barrier.
// ---------------------------------------------------------------------------
__global__ __launch_bounds__(384) void k_recur(
    const _Float16* __restrict__ gx, const float* __restrict__ att,
    const float* __restrict__ h0, const f16x8* __restrict__ wfh,
    const float* __restrict__ bhh, _Float16* __restrict__ hb,
    unsigned int* __restrict__ ctr, float* __restrict__ out,
    float* __restrict__ hx)
{
    const int bid = blockIdx.x;
    const int g = bid >> 4;
    const int c = bid & 15;
    const int t = threadIdx.x;
    const int w = t >> 6;                        // 0..5
    const int l = t & 63;

    __shared__ _Float16 h16[32 * 512];           // 32KB, XOR-swizzled rows
    __shared__ float ghs[96][33];                // gh slice, padded
    __shared__ float hold[32][32];               // local h patch, f32

    // --- B fragments: wave w holds its 16 kk-frags in registers forever ---
    f16x8 B[16];
    {
        const f16x8* p = wfh + (size_t)(c * 6 + w) * 1024 + l;
        #pragma unroll
        for (int kk = 0; kk < 16; ++kk) B[kk] = p[kk * 64];
    }

    // --- biases for this thread's gate elements (<=3), hoisted ---
    float bhr[3], bhz[3], bhn[3];
    {
        int ne = 0;
        for (int e = t; e < 1024; e += 384, ++ne) {
            const int jl = e & 31;
            bhr[ne] = bhh[c * 32 + jl];
            bhz[ne] = bhh[512 + c * 32 + jl];
            bhn[ne] = bhh[1024 + c * 32 + jl];
        }
    }

    // --- local h patch init from h0 (f32) ---
    for (int e = t; e < 1024; e += 384) {
        const int i = e >> 5, jl = e & 31;
        hold[i][jl] = h0[(size_t)(g * 32 + i) * 512 + c * 32 + jl];
    }

    const int ib = (l >> 4) * 4;
    const int nl = w * 16 + (l & 15);

    for (int s = 0; s < LDIM; ++s) {
        const int par = s & 1;
        const _Float16* hsrc = hb + (size_t)par * (512 * 512) + (size_t)g * 32 * 512;

        // --- prefetch gate inputs into registers (in flight during stage) ---
        float pxr[3], pxz[3], pxn[3], patt[3];
        {
            int ne = 0;
            for (int e = t; e < 1024; e += 384, ++ne) {
                const int i = e >> 5, jl = e & 31;
                const _Float16* gr = gx + ((size_t)s * 512 + g * 32 + i) * GDIM + c * 32 + jl;
                pxr[ne] = (float)gr[0];
                pxz[ne] = (float)gr[512];
                pxn[ne] = (float)gr[1024];
                patt[ne] = att[(size_t)s * BDIM + g * 32 + i];
            }
        }

        // --- stage h (f16) into swizzled LDS: 256 threads x 128B ---
        if (t < 256) {
            const int i  = t >> 3;
            const int kc = (t & 7) * 64;         // f16 index
            const _Float16* src = hsrc + i * 512 + kc;
            #pragma unroll
            for (int q = 0; q < 8; ++q) {
                const int byte = i * 1024 + kc * 2 + q * 16;
                const int sw = byte ^ ((i & 7) << 4);
                *reinterpret_cast<f16x8*>(reinterpret_cast<char*>(h16) + sw) =
                    *reinterpret_cast<const f16x8*>(src + q * 8);
            }
        }
        __syncthreads();

        // --- MFMA: gh[mt*16+i][w*16+(l&15)] over K=512 ---
        f32x4 acc0 = {0.f, 0.f, 0.f, 0.f};
        f32x4 acc1 = {0.f, 0.f, 0.f, 0.f};
        {
            const int k8 = (l >> 4) * 8;
            const int rr0 = l & 15;
            const int rr1 = rr0 + 16;
            #pragma unroll
            for (int kk = 0; kk < 16; ++kk) {
                const int kb = (kk * 32 + k8) * 2;
                const int b0 = (rr0 * 1024 + kb) ^ ((rr0 & 7) << 4);
                const int b1 = (rr1 * 1024 + kb) ^ ((rr1 & 7) << 4);
                const f16x8 a0 = *reinterpret_cast<const f16x8*>(
                    reinterpret_cast<const char*>(h16) + b0);
                const f16x8 a1 = *reinterpret_cast<const f16x8*>(
                    reinterpret_cast<const char*>(h16) + b1);
                acc0 = __builtin_amdgcn_mfma_f32_16x16x32_f16(a0, B[kk], acc0, 0, 0, 0);
                acc1 = __builtin_amdgcn_mfma_f32_16x16x32_f16(a1, B[kk], acc1, 0, 0, 0);
            }
        }
        #pragma unroll
        for (int q = 0; q < 4; ++q) {
            ghs[nl][ib + q]      = acc0[q];
            ghs[nl][16 + ib + q] = acc1[q];
        }
        __syncthreads();

        // --- gates + h update (local patch stays f32) ---
        _Float16* hdst = hb + (size_t)(par ^ 1) * (512 * 512) + (size_t)g * 32 * 512;
        {
            int ne = 0;
            for (int e = t; e < 1024; e += 384, ++ne) {
                const int i = e >> 5, jl = e & 31;
                const float hr = ghs[jl][i]      + bhr[ne];
                const float hz = ghs[32 + jl][i] + bhz[ne];
                const float hn = ghs[64 + jl][i] + bhn[ne];
                const float h  = hold[i][jl];
                const float rg = 1.f / (1.f + __expf(-(pxr[ne] + hr)));
                const float zg = 1.f / (1.f + __expf(-(pxz[ne] + hz)));
                const float ng = tanhf(pxn[ne] + rg * hn);
                const float ho = (1.f - zg) * ng + zg * h;
                const float wv = patt[ne];
                const float hnew = (1.f - wv) * h + wv * ho;
                hold[i][jl] = hnew;
                out[((size_t)(g * 32 + i) * LDIM + s) * 512 + c * 32 + jl] = hnew;
                hdst[i * 512 + c * 32 + jl] = (_Float16)hnew;
            }
        }

        // --- per-group 16-block barrier (agent scope, per-step flag) ---
        __syncthreads();
        if (t == 0) {
            unsigned int* p = ctr + g * LDIM + s;
            __hip_atomic_fetch_add(p, 1u, __ATOMIC_ACQ_REL, __HIP_MEMORY_SCOPE_AGENT);
            while (__hip_atomic_load(p, __ATOMIC_ACQUIRE, __HIP_MEMORY_SCOPE_AGENT) < NCOL)
                __builtin_amdgcn_s_sleep(1);
        }
        __syncthreads();
    }

    for (int e = t; e < 1024; e += 384) {
        const int i = e >> 5, jl = e & 31;
        hx[(size_t)(g * 32 + i) * 512 + c * 32 + jl] = hold[i][jl];
    }
}

// ---------------------------------------------------------------------------
extern "C" void kernel_launch(void* const* d_in, const int* in_sizes, int n_in,
                              void* d_out, int out_size, void* d_ws, size_t ws_size,
                              hipStream_t stream)
{
    const float* x   = (const float*)d_in[0];
    const float* att = (const float*)d_in[1];
    const float* h0  = (const float*)d_in[2];
    const float* wih = (const float*)d_in[3];
    const float* whh = (const float*)d_in[4];
    const float* bih = (const float*)d_in[5];
    const float* bhh = (const float*)d_in[6];

    float* out = (float*)d_out;
    float* hx  = out + (size_t)BDIM * LDIM * HDIM;

    // ws layout (region A reused: wfi for K1, then wfh for K2):
    //   A   @ 0x000000  (1.5MB fragment-packed weights)
    //   ctr @ 0x180000  (16*200 u32)
    //   hb  @ 0x190000  (2 x 512KB f16 h exchange)
    //   gx  @ 0x290000  (300MB f16)
    char* ws = (char*)d_ws;
    f16x8*        wfA = (f16x8*)ws;
    unsigned int* ctr = (unsigned int*)(ws + 0x180000);
    _Float16*     hb  = (_Float16*)(ws + 0x190000);
    _Float16*     gx  = (_Float16*)(ws + 0x290000);

    k_init<<<1024, 256, 0, stream>>>(ctr, h0, hb);
    k_pack_wfi<<<384, 256, 0, stream>>>(wih, wfA);
    k_gemm_gx<<<9600, 256, 0, stream>>>(x, wfA, bih, gx);
    k_pack_wfh<<<384, 256, 0, stream>>>(whh, wfA);   // overwrites wfi (gemm done)
    k_recur<<<256, 384, 0, stream>>>(gx, att, h0, wfA, bhh, hb, ctr, out, hx);
}

// Round 5
// 1529.743 us; speedup vs baseline: 11.0581x; 2.4742x over previous
//
#include <hip/hip_runtime.h>
#include <hip/hip_fp16.h>

#define LDIM 200
#define BDIM 512
#define IDIM 512
#define HDIM 512
#define GDIM 1536  // 3*H
#define NGRP 16    // batch groups (32 rows each)
#define NCOL 16    // col groups   (32 h-cols each)

typedef _Float16 f16x8 __attribute__((ext_vector_type(8)));
typedef _Float16 f16x4 __attribute__((ext_vector_type(4)));
typedef float    f32x4 __attribute__((ext_vector_type(4)));

// ---------------------------------------------------------------------------
// k_init: zero per-block flags; convert h0 -> hb buffer 0 (f16)
// ---------------------------------------------------------------------------
__global__ __launch_bounds__(256) void k_init(
    unsigned int* __restrict__ flags, const float* __restrict__ h0,
    _Float16* __restrict__ hb)
{
    int i = blockIdx.x * 256 + threadIdx.x;
    if (i < NGRP * NCOL) flags[i] = 0;
    if (i < BDIM * HDIM) hb[i] = (_Float16)h0[i];
}

// ---------------------------------------------------------------------------
// k_pack_wfi: pack w_ih (f32 [1536][512]) into MFMA B-fragment order, f16.
// (round-3 verified)
// ---------------------------------------------------------------------------
__global__ __launch_bounds__(256) void k_pack_wfi(
    const float* __restrict__ w, f16x8* __restrict__ wf)
{
    int u = blockIdx.x * 256 + threadIdx.x;
    if (u >= (GDIM / 16) * 16 * 64) return;
    const int lane = u & 63;
    const int kk   = (u >> 6) & 15;
    const int ntg  = u >> 10;
    const int n = ntg * 16 + (lane & 15);
    const int k = kk * 32 + (lane >> 4) * 8;
    const float* src = w + (size_t)n * IDIM + k;
    f16x8 v;
    #pragma unroll
    for (int j = 0; j < 8; ++j) v[j] = (_Float16)src[j];
    wf[u] = v;
}

// ---------------------------------------------------------------------------
// k_pack_wfh: pack w_hh into per-colgroup fragment order. (round-3 verified)
// ---------------------------------------------------------------------------
__global__ __launch_bounds__(256) void k_pack_wfh(
    const float* __restrict__ w, f16x8* __restrict__ wf)
{
    int u = blockIdx.x * 256 + threadIdx.x;
    if (u >= NCOL * 6 * 16 * 64) return;
    const int lane = u & 63;
    const int kk   = (u >> 6) & 15;
    const int cw   = u >> 10;
    const int wv   = cw % 6;
    const int c    = cw / 6;
    const int n_local = wv * 16 + (lane & 15);
    const int gate    = n_local >> 5;
    const int j_local = n_local & 31;
    const int n = gate * 512 + c * 32 + j_local;
    const int k = kk * 32 + (lane >> 4) * 8;
    const float* src = w + (size_t)n * HDIM + k;
    f16x8 v;
    #pragma unroll
    for (int j = 0; j < 8; ++j) v[j] = (_Float16)src[j];
    wf[u] = v;
}

// ---------------------------------------------------------------------------
// K1: gx = x @ w_ih^T + b_ih (f16 out). (round-3 verified)
// ---------------------------------------------------------------------------
__global__ __launch_bounds__(256) void k_gemm_gx(
    const float* __restrict__ x, const f16x8* __restrict__ wfi,
    const float* __restrict__ bih, _Float16* __restrict__ gx)
{
    const int bid  = blockIdx.x;
    const int xcd  = bid & 7;
    const int slot = bid >> 3;
    const int gl   = slot / 12;
    const int j    = slot - gl * 12;
    const int m0   = (xcd * 100 + gl) * 128;
    const int n0   = j * 128;

    const int t = threadIdx.x;
    const int w = t >> 6;
    const int l = t & 63;
    const int mw = m0 + w * 32;
    const int ko = (l >> 4) * 8;

    const int r0 = mw + (l & 15);
    const int r1 = r0 + 16;
    const float* a0 = x + ((size_t)(r0 & 511) * LDIM + (r0 >> 9)) * IDIM;
    const float* a1 = x + ((size_t)(r1 & 511) * LDIM + (r1 >> 9)) * IDIM;
    const f16x8* bp = wfi + (size_t)(j * 8) * 1024 + l;

    f32x4 acc[2][8] = {};

    for (int kk = 0; kk < 16; ++kk) {
        const int k = kk * 32 + ko;
        f16x8 af[2];
        {
            const float4 v0 = *reinterpret_cast<const float4*>(a0 + k);
            const float4 v1 = *reinterpret_cast<const float4*>(a0 + k + 4);
            const float4 v2 = *reinterpret_cast<const float4*>(a1 + k);
            const float4 v3 = *reinterpret_cast<const float4*>(a1 + k + 4);
            af[0][0] = (_Float16)v0.x; af[0][1] = (_Float16)v0.y;
            af[0][2] = (_Float16)v0.z; af[0][3] = (_Float16)v0.w;
            af[0][4] = (_Float16)v1.x; af[0][5] = (_Float16)v1.y;
            af[0][6] = (_Float16)v1.z; af[0][7] = (_Float16)v1.w;
            af[1][0] = (_Float16)v2.x; af[1][1] = (_Float16)v2.y;
            af[1][2] = (_Float16)v2.z; af[1][3] = (_Float16)v2.w;
            af[1][4] = (_Float16)v3.x; af[1][5] = (_Float16)v3.y;
            af[1][6] = (_Float16)v3.z; af[1][7] = (_Float16)v3.w;
        }
        const f16x8* bk = bp + kk * 64;
        #pragma unroll
        for (int nt = 0; nt < 8; ++nt) {
            const f16x8 bf = bk[(size_t)nt * 1024];
            acc[0][nt] = __builtin_amdgcn_mfma_f32_16x16x32_f16(af[0], bf, acc[0][nt], 0, 0, 0);
            acc[1][nt] = __builtin_amdgcn_mfma_f32_16x16x32_f16(af[1], bf, acc[1][nt], 0, 0, 0);
        }
    }

    #pragma unroll
    for (int nt = 0; nt < 8; ++nt) {
        const int n = n0 + nt * 16 + (l & 15);
        const float bv = bih[n];
        #pragma unroll
        for (int mt = 0; mt < 2; ++mt) {
            #pragma unroll
            for (int r = 0; r < 4; ++r) {
                const int m = mw + mt * 16 + (l >> 4) * 4 + r;
                gx[(size_t)m * GDIM + n] = (_Float16)(acc[mt][nt][r] + bv);
            }
        }
    }
}

// ---------------------------------------------------------------------------
// K2: persistent recurrence. 256 blocks = 16 batch-groups x 16 col-groups,
// 384 threads. w_hh slice in registers. Cross-block exchange via Infinity
// Cache: ALL hb/flag traffic uses sc0 sc1 (system-scope) loads/stores ->
// no L2 flush/invalidate ever. Monotonic per-block flags, 3-buffered hb.
// (Blocks provably stay within 1 step of each other -> triple buffer safe.)
// ---------------------------------------------------------------------------
__global__ __launch_bounds__(384) void k_recur(
    const _Float16* __restrict__ gx, const float* __restrict__ att,
    const float* __restrict__ h0, const f16x8* __restrict__ wfh,
    const float* __restrict__ bhh, _Float16* __restrict__ hb,
    unsigned int* __restrict__ flags, float* __restrict__ out,
    float* __restrict__ hx)
{
    const int bid = blockIdx.x;
    const int g = bid >> 4;
    const int c = bid & 15;
    const int t = threadIdx.x;
    const int w = t >> 6;                        // 0..5
    const int l = t & 63;

    __shared__ __align__(16) _Float16 h16[32 * 512];   // 32KB, XOR-swizzled
    __shared__ float ghs[96][33];                      // gh slice (n-major)

    // --- B fragments: wave w holds its 16 kk-frags in registers forever ---
    f16x8 B[16];
    {
        const f16x8* p = wfh + (size_t)(c * 6 + w) * 1024 + l;
        #pragma unroll
        for (int kk = 0; kk < 16; ++kk) B[kk] = p[kk * 64];
    }

    // --- gate-phase mapping: thread t<256 owns row i, cols j4..j4+3 ---
    const int i  = t >> 3;
    const int j4 = (t & 7) * 4;

    float bhr[4], bhz[4], bhn[4], hv[4];
    if (t < 256) {
        const float4 r4 = *(const float4*)(bhh + c * 32 + j4);
        const float4 z4 = *(const float4*)(bhh + 512 + c * 32 + j4);
        const float4 n4 = *(const float4*)(bhh + 1024 + c * 32 + j4);
        bhr[0]=r4.x; bhr[1]=r4.y; bhr[2]=r4.z; bhr[3]=r4.w;
        bhz[0]=z4.x; bhz[1]=z4.y; bhz[2]=z4.z; bhz[3]=z4.w;
        bhn[0]=n4.x; bhn[1]=n4.y; bhn[2]=n4.z; bhn[3]=n4.w;
        const float4 h4 = *(const float4*)(h0 + (size_t)(g * 32 + i) * 512 + c * 32 + j4);
        hv[0]=h4.x; hv[1]=h4.y; hv[2]=h4.z; hv[3]=h4.w;
    }

    const unsigned int* fline = flags + g * 16;
    unsigned int* myflag = flags + g * 16 + c;

    const int ib = (l >> 4) * 4;
    const int nl = w * 16 + (l & 15);
    const int k8 = (l >> 4) * 8;
    const int rr0 = l & 15;
    const int rr1 = rr0 + 16;

    int rd = 0;                                  // hb read buffer = s % 3
    for (int s = 0; s < LDIM; ++s) {
        // --- prefetch gate inputs (plain loads; in flight across the spin) ---
        f16x4 gr_r = {}, gr_z = {}, gr_n = {};
        float av = 0.f;
        if (t < 256) {
            const _Float16* gp = gx + ((size_t)s * BDIM + g * 32 + i) * GDIM + c * 32 + j4;
            gr_r = *(const f16x4*)(gp);
            gr_z = *(const f16x4*)(gp + 512);
            gr_n = *(const f16x4*)(gp + 1024);
            av = att[(size_t)s * BDIM + g * 32 + i];
        }

        // --- barrier: wave 0 waits until all 16 flags >= s ---
        if (s > 0 && w == 0) {
            const unsigned int* fp = fline + (l & 15);
            unsigned int fv;
            do {
                asm volatile("global_load_dword %0, %1, off sc0 sc1\n\t"
                             "s_waitcnt vmcnt(0)"
                             : "=v"(fv) : "v"(fp) : "memory");
            } while (fv < (unsigned int)s);
        }
        __syncthreads();

        // --- stage h from hb[rd] into swizzled LDS (coherent IF loads) ---
        // patch = 32 rows x 512 f16 = 4096 u64 units, 128 units/row.
        if (t < 256) {
            const unsigned long long* hsrc = (const unsigned long long*)
                (hb + (size_t)rd * (BDIM * HDIM) + (size_t)g * 32 * 512);
            unsigned long long vv[16];
            #pragma unroll
            for (int q = 0; q < 16; ++q) {
                asm volatile("global_load_dwordx2 %0, %1, off sc0 sc1"
                             : "=v"(vv[q]) : "v"(hsrc + q * 256 + t));
            }
            asm volatile("s_waitcnt vmcnt(0)" ::: "memory");
            __builtin_amdgcn_sched_barrier(0);
            #pragma unroll
            for (int q = 0; q < 16; ++q) {
                const int idx = q * 256 + t;     // u64 unit, row-major
                const int row = idx >> 7;        // 128 u64 per row
                const int c8  = idx & 127;
                const int byte = (row * 1024 + c8 * 8) ^ ((row & 7) << 4);
                *(unsigned long long*)((char*)h16 + byte) = vv[q];
            }
        }
        __syncthreads();

        // --- MFMA: gh over K=512, wave w -> ghs rows w*16..+16 ---
        f32x4 acc0 = {0.f, 0.f, 0.f, 0.f};
        f32x4 acc1 = {0.f, 0.f, 0.f, 0.f};
        #pragma unroll
        for (int kk = 0; kk < 16; ++kk) {
            const int kb = kk * 64 + k8 * 2;
            const int b0 = (rr0 * 1024 + kb) ^ ((rr0 & 7) << 4);
            const int b1 = (rr1 * 1024 + kb) ^ ((rr1 & 7) << 4);
            const f16x8 a0 = *(const f16x8*)((const char*)h16 + b0);
            const f16x8 a1 = *(const f16x8*)((const char*)h16 + b1);
            acc0 = __builtin_amdgcn_mfma_f32_16x16x32_f16(a0, B[kk], acc0, 0, 0, 0);
            acc1 = __builtin_amdgcn_mfma_f32_16x16x32_f16(a1, B[kk], acc1, 0, 0, 0);
        }
        #pragma unroll
        for (int q = 0; q < 4; ++q) {
            ghs[nl][ib + q]      = acc0[q];
            ghs[nl][16 + ib + q] = acc1[q];
        }
        __syncthreads();

        // --- gates + h update (h patch in registers) ---
        const int wr = (rd == 2) ? 0 : rd + 1;
        if (t < 256) {
            float o[4];
            f16x4 hp;
            #pragma unroll
            for (int q = 0; q < 4; ++q) {
                const int jl = j4 + q;
                const float hr = ghs[jl][i]      + bhr[q];
                const float hz = ghs[32 + jl][i] + bhz[q];
                const float hn = ghs[64 + jl][i] + bhn[q];
                const float h  = hv[q];
                const float rg = 1.f / (1.f + __expf(-((float)gr_r[q] + hr)));
                const float zg = 1.f / (1.f + __expf(-((float)gr_z[q] + hz)));
                const float ng = tanhf((float)gr_n[q] + rg * hn);
                const float ho = (1.f - zg) * ng + zg * h;
                const float hnew = (1.f - av) * h + av * ho;
                hv[q] = hnew;
                o[q] = hnew;
                hp[q] = (_Float16)hnew;
            }
            *(float4*)(out + ((size_t)(g * 32 + i) * LDIM + s) * HDIM + c * 32 + j4)
                = *(float4*)o;
            union { f16x4 v; unsigned long long u; } pk; pk.v = hp;
            _Float16* hd = hb + (size_t)wr * (BDIM * HDIM)
                         + (size_t)(g * 32 + i) * 512 + c * 32 + j4;
            asm volatile("global_store_dwordx2 %0, %1, off sc0 sc1"
                         :: "v"(hd), "v"(pk.u) : "memory");
        }
        asm volatile("s_waitcnt vmcnt(0)" ::: "memory");
        __syncthreads();
        if (t == 0) {
            unsigned int fv = (unsigned int)(s + 1);
            asm volatile("global_store_dword %0, %1, off sc0 sc1"
                         :: "v"(myflag), "v"(fv) : "memory");
        }
        rd = wr;
    }

    if (t < 256) {
        float o[4] = {hv[0], hv[1], hv[2], hv[3]};
        *(float4*)(hx + (size_t)(g * 32 + i) * 512 + c * 32 + j4) = *(float4*)o;
    }
}

// ---------------------------------------------------------------------------
extern "C" void kernel_launch(void* const* d_in, const int* in_sizes, int n_in,
                              void* d_out, int out_size, void* d_ws, size_t ws_size,
                              hipStream_t stream)
{
    const float* x   = (const float*)d_in[0];
    const float* att = (const float*)d_in[1];
    const float* h0  = (const float*)d_in[2];
    const float* wih = (const float*)d_in[3];
    const float* whh = (const float*)d_in[4];
    const float* bih = (const float*)d_in[5];
    const float* bhh = (const float*)d_in[6];

    float* out = (float*)d_out;
    float* hx  = out + (size_t)BDIM * LDIM * HDIM;

    // ws layout:
    //   wfA   @ 0x000000  (1.5MB fragment-packed weights; reused wfi->wfh)
    //   flags @ 0x180000  (256 u32)
    //   hb    @ 0x190000  (3 x 512KB f16 h exchange)
    //   gx    @ 0x310000  (~302MB f16)
    char* ws = (char*)d_ws;
    f16x8*        wfA   = (f16x8*)ws;
    unsigned int* flags = (unsigned int*)(ws + 0x180000);
    _Float16*     hb    = (_Float16*)(ws + 0x190000);
    _Float16*     gx    = (_Float16*)(ws + 0x310000);

    k_init<<<1024, 256, 0, stream>>>(flags, h0, hb);
    k_pack_wfi<<<384, 256, 0, stream>>>(wih, wfA);
    k_gemm_gx<<<9600, 256, 0, stream>>>(x, wfA, bih, gx);
    k_pack_wfh<<<384, 256, 0, stream>>>(whh, wfA);   // overwrites wfi (gemm done)
    k_recur<<<256, 384, 0, stream>>>(gx, att, h0, wfA, bhh, hb, flags, out, hx);
}

// Round 6
// 1360.241 us; speedup vs baseline: 12.4361x; 1.1246x over previous
//
#include <hip/hip_runtime.h>
#include <hip/hip_fp16.h>

#define LDIM 200
#define BDIM 512
#define IDIM 512
#define HDIM 512
#define GDIM 1536  // 3*H
#define NGRP 16    // batch groups (32 rows each)
#define NCOL 16    // col groups   (32 h-cols each)

typedef _Float16 f16x8 __attribute__((ext_vector_type(8)));
typedef _Float16 f16x4 __attribute__((ext_vector_type(4)));
typedef float    f32x4 __attribute__((ext_vector_type(4)));

// ---------------------------------------------------------------------------
// k_init: zero per-block flags; convert h0 -> hb buffer 0 (f16)
// ---------------------------------------------------------------------------
__global__ __launch_bounds__(256) void k_init(
    unsigned int* __restrict__ flags, const float* __restrict__ h0,
    _Float16* __restrict__ hb)
{
    int i = blockIdx.x * 256 + threadIdx.x;
    if (i < NGRP * NCOL) flags[i] = 0;
    if (i < BDIM * HDIM) hb[i] = (_Float16)h0[i];
}

// ---------------------------------------------------------------------------
// k_pack_wfi: pack w_ih (f32 [1536][512]) into MFMA B-fragment order, f16.
// unit u = (ntg*16+kk)*64+lane ; n = ntg*16+(lane&15), k = kk*32+(lane>>4)*8+j
// (round-3 verified)
// ---------------------------------------------------------------------------
__global__ __launch_bounds__(256) void k_pack_wfi(
    const float* __restrict__ w, f16x8* __restrict__ wf)
{
    int u = blockIdx.x * 256 + threadIdx.x;
    if (u >= (GDIM / 16) * 16 * 64) return;
    const int lane = u & 63;
    const int kk   = (u >> 6) & 15;
    const int ntg  = u >> 10;
    const int n = ntg * 16 + (lane & 15);
    const int k = kk * 32 + (lane >> 4) * 8;
    const float* src = w + (size_t)n * IDIM + k;
    f16x8 v;
    #pragma unroll
    for (int j = 0; j < 8; ++j) v[j] = (_Float16)src[j];
    wf[u] = v;
}

// ---------------------------------------------------------------------------
// k_pack_wfh: pack w_hh into per-colgroup fragment order. (round-3 verified)
// ---------------------------------------------------------------------------
__global__ __launch_bounds__(256) void k_pack_wfh(
    const float* __restrict__ w, f16x8* __restrict__ wf)
{
    int u = blockIdx.x * 256 + threadIdx.x;
    if (u >= NCOL * 6 * 16 * 64) return;
    const int lane = u & 63;
    const int kk   = (u >> 6) & 15;
    const int cw   = u >> 10;
    const int wv   = cw % 6;
    const int c    = cw / 6;
    const int n_local = wv * 16 + (lane & 15);
    const int gate    = n_local >> 5;
    const int j_local = n_local & 31;
    const int n = gate * 512 + c * 32 + j_local;
    const int k = kk * 32 + (lane >> 4) * 8;
    const float* src = w + (size_t)n * HDIM + k;
    f16x8 v;
    #pragma unroll
    for (int j = 0; j < 8; ++j) v[j] = (_Float16)src[j];
    wf[u] = v;
}

// ---------------------------------------------------------------------------
// K1 v2: gx = x @ w_ih^T + b_ih (f16 out).  BM=64, BN=512, K=512 whole.
// 256 threads / 4 waves; wave wid owns n-quarter wid*128.  A staged once in
// 64KB XOR-swizzled LDS (same swizzle formulas as verified k_recur staging).
// B from fragment-packed wfi (L2-resident).  Grid 4800 = 8 xcd x 200 gl x 3 ng;
// the 3 n-groups of one m-tile are consecutive slots -> same XCD -> x L2-reuse.
// ---------------------------------------------------------------------------
__global__ __launch_bounds__(256, 2) void k_gemm_gx(
    const float* __restrict__ x, const f16x8* __restrict__ wfi,
    const float* __restrict__ bih, _Float16* __restrict__ gx)
{
    const int bid  = blockIdx.x;
    const int xcd  = bid & 7;
    const int slot = bid >> 3;          // 0..599
    const int gl   = slot / 3;          // 0..199
    const int ng   = slot % 3;          // 0..2
    const int m0   = (xcd * 200 + gl) * 64;
    const int n0   = ng * 512;

    const int t   = threadIdx.x;
    const int wid = t >> 6;             // n-quarter 0..3
    const int l   = t & 63;

    __shared__ __align__(16) _Float16 As[64 * 512];    // 64KB, XOR-swizzled

    // --- stage A tile: thread t -> row r = t>>2, k-range (t&3)*128..+128 ---
    {
        const int r  = t >> 2;
        const int k0 = (t & 3) * 128;
        const int m  = m0 + r;
        const float* src = x + ((size_t)(m & 511) * LDIM + (m >> 9)) * IDIM + k0;
        #pragma unroll
        for (int jj = 0; jj < 16; ++jj) {
            const float4 v0 = *(const float4*)(src + jj * 8);
            const float4 v1 = *(const float4*)(src + jj * 8 + 4);
            f16x8 hq;
            hq[0] = (_Float16)v0.x; hq[1] = (_Float16)v0.y;
            hq[2] = (_Float16)v0.z; hq[3] = (_Float16)v0.w;
            hq[4] = (_Float16)v1.x; hq[5] = (_Float16)v1.y;
            hq[6] = (_Float16)v1.z; hq[7] = (_Float16)v1.w;
            const int byte = (r * 1024 + (k0 + jj * 8) * 2) ^ ((r & 7) << 4);
            *(f16x8*)((char*)As + byte) = hq;
        }
    }
    __syncthreads();

    const f16x8* bp = wfi + (size_t)((ng * 4 + wid) * 8) * 1024 + l;
    const int kb8   = (l >> 4) * 16;    // byte offset of lane's k-oct
    const int rbase = l & 15;

    f32x4 acc[4][8] = {};

    for (int kk = 0; kk < 16; ++kk) {
        f16x8 a[4];
        #pragma unroll
        for (int mt = 0; mt < 4; ++mt) {
            const int r = mt * 16 + rbase;
            const int byte = (r * 1024 + kk * 64 + kb8) ^ ((r & 7) << 4);
            a[mt] = *(const f16x8*)((const char*)As + byte);
        }
        const f16x8* bk = bp + kk * 64;
        #pragma unroll
        for (int nt = 0; nt < 8; ++nt) {
            const f16x8 bf = bk[(size_t)nt * 1024];
            #pragma unroll
            for (int mt = 0; mt < 4; ++mt)
                acc[mt][nt] = __builtin_amdgcn_mfma_f32_16x16x32_f16(a[mt], bf, acc[mt][nt], 0, 0, 0);
        }
    }

    // --- epilogue (same D mapping as verified K1) ---
    #pragma unroll
    for (int nt = 0; nt < 8; ++nt) {
        const int n = n0 + wid * 128 + nt * 16 + (l & 15);
        const float bv = bih[n];
        #pragma unroll
        for (int mt = 0; mt < 4; ++mt) {
            #pragma unroll
            for (int r = 0; r < 4; ++r) {
                const int m = m0 + mt * 16 + (l >> 4) * 4 + r;
                gx[(size_t)m * GDIM + n] = (_Float16)(acc[mt][nt][r] + bv);
            }
        }
    }
}

// ---------------------------------------------------------------------------
// K2: persistent recurrence. 256 blocks = 16 batch-groups x 16 col-groups,
// 384 threads. w_hh slice in registers. Exchange via IF with sc0 sc1 (no L2
// flushes), monotonic flags, 3-buffered hb (round-5 verified protocol).
// New this round: 1-step-ahead gate prefetch, out-stores after flag,
// transposed ghsT for conflict-free float4 gate reads.
// ---------------------------------------------------------------------------
__global__ __launch_bounds__(384) void k_recur(
    const _Float16* __restrict__ gx, const float* __restrict__ att,
    const float* __restrict__ h0, const f16x8* __restrict__ wfh,
    const float* __restrict__ bhh, _Float16* __restrict__ hb,
    unsigned int* __restrict__ flags, float* __restrict__ out,
    float* __restrict__ hx)
{
    const int bid = blockIdx.x;
    const int g = bid >> 4;
    const int c = bid & 15;
    const int t = threadIdx.x;
    const int w = t >> 6;                        // 0..5
    const int l = t & 63;

    __shared__ __align__(16) _Float16 h16[32 * 512];   // 32KB, XOR-swizzled
    __shared__ float ghsT[32][100];                    // gh slice [row][n]

    // --- B fragments: wave w holds its 16 kk-frags in registers forever ---
    f16x8 B[16];
    {
        const f16x8* p = wfh + (size_t)(c * 6 + w) * 1024 + l;
        #pragma unroll
        for (int kk = 0; kk < 16; ++kk) B[kk] = p[kk * 64];
    }

    // --- gate-phase mapping: thread t<256 owns row i, cols j4..j4+3 ---
    const int i  = t >> 3;
    const int j4 = (t & 7) * 4;

    float bhr[4], bhz[4], bhn[4], hv[4];
    if (t < 256) {
        const float4 r4 = *(const float4*)(bhh + c * 32 + j4);
        const float4 z4 = *(const float4*)(bhh + 512 + c * 32 + j4);
        const float4 n4 = *(const float4*)(bhh + 1024 + c * 32 + j4);
        bhr[0]=r4.x; bhr[1]=r4.y; bhr[2]=r4.z; bhr[3]=r4.w;
        bhz[0]=z4.x; bhz[1]=z4.y; bhz[2]=z4.z; bhz[3]=z4.w;
        bhn[0]=n4.x; bhn[1]=n4.y; bhn[2]=n4.z; bhn[3]=n4.w;
        const float4 h4 = *(const float4*)(h0 + (size_t)(g * 32 + i) * 512 + c * 32 + j4);
        hv[0]=h4.x; hv[1]=h4.y; hv[2]=h4.z; hv[3]=h4.w;
    }

    const unsigned int* fline = flags + g * 16;
    unsigned int* myflag = flags + g * 16 + c;

    const int ib = (l >> 4) * 4;
    const int nl = w * 16 + (l & 15);
    const int k8 = (l >> 4) * 8;
    const int rr0 = l & 15;
    const int rr1 = rr0 + 16;

    // --- prologue: gate inputs for step 0 ---
    f16x4 cr = {}, cz = {}, cn = {};
    float ca = 0.f;
    if (t < 256) {
        const _Float16* gp = gx + ((size_t)(g * 32 + i)) * GDIM + c * 32 + j4;
        cr = *(const f16x4*)(gp);
        cz = *(const f16x4*)(gp + 512);
        cn = *(const f16x4*)(gp + 1024);
        ca = att[g * 32 + i];
    }

    int rd = 0;                                  // hb read buffer = s % 3
    for (int s = 0; s < LDIM; ++s) {
        // --- barrier: wave 0 waits until all 16 flags >= s ---
        if (s > 0 && w == 0) {
            const unsigned int* fp = fline + (l & 15);
            unsigned int fv;
            do {
                asm volatile("global_load_dword %0, %1, off sc0 sc1\n\t"
                             "s_waitcnt vmcnt(0)"
                             : "=v"(fv) : "v"(fp) : "memory");
            } while (fv < (unsigned int)s);
        }
        __syncthreads();

        // --- stage h from hb[rd] into swizzled LDS (coherent IF loads) ---
        // patch = 32 rows x 512 f16 = 4096 u64 units, 128 units/row.
        if (t < 256) {
            const unsigned long long* hsrc = (const unsigned long long*)
                (hb + (size_t)rd * (BDIM * HDIM) + (size_t)g * 32 * 512);
            unsigned long long vv[16];
            #pragma unroll
            for (int q = 0; q < 16; ++q) {
                asm volatile("global_load_dwordx2 %0, %1, off sc0 sc1"
                             : "=v"(vv[q]) : "v"(hsrc + q * 256 + t));
            }
            asm volatile("s_waitcnt vmcnt(0)" ::: "memory");
            __builtin_amdgcn_sched_barrier(0);
            #pragma unroll
            for (int q = 0; q < 16; ++q) {
                const int idx = q * 256 + t;     // u64 unit, row-major
                const int row = idx >> 7;        // 128 u64 per row
                const int c8  = idx & 127;
                const int byte = (row * 1024 + c8 * 8) ^ ((row & 7) << 4);
                *(unsigned long long*)((char*)h16 + byte) = vv[q];
            }
        }

        // --- 1-step-ahead gate prefetch (hidden under MFMA + gates) ---
        f16x4 nr = {}, nz = {}, nn2 = {};
        float na = 0.f;
        if (t < 256) {
            const int sn = (s < LDIM - 1) ? s + 1 : s;
            const _Float16* gp = gx + ((size_t)sn * BDIM + g * 32 + i) * GDIM + c * 32 + j4;
            nr  = *(const f16x4*)(gp);
            nz  = *(const f16x4*)(gp + 512);
            nn2 = *(const f16x4*)(gp + 1024);
            na  = att[(size_t)sn * BDIM + g * 32 + i];
        }
        __syncthreads();

        // --- MFMA: gh over K=512, wave w -> ghsT cols w*16..+16 ---
        f32x4 acc0 = {0.f, 0.f, 0.f, 0.f};
        f32x4 acc1 = {0.f, 0.f, 0.f, 0.f};
        #pragma unroll
        for (int kk = 0; kk < 16; ++kk) {
            const int kb = kk * 64 + k8 * 2;
            const int b0 = (rr0 * 1024 + kb) ^ ((rr0 & 7) << 4);
            const int b1 = (rr1 * 1024 + kb) ^ ((rr1 & 7) << 4);
            const f16x8 a0 = *(const f16x8*)((const char*)h16 + b0);
            const f16x8 a1 = *(const f16x8*)((const char*)h16 + b1);
            acc0 = __builtin_amdgcn_mfma_f32_16x16x32_f16(a0, B[kk], acc0, 0, 0, 0);
            acc1 = __builtin_amdgcn_mfma_f32_16x16x32_f16(a1, B[kk], acc1, 0, 0, 0);
        }
        #pragma unroll
        for (int q = 0; q < 4; ++q) {
            ghsT[ib + q][nl]      = acc0[q];
            ghsT[16 + ib + q][nl] = acc1[q];
        }
        __syncthreads();

        // --- gates + h update (h patch in registers) ---
        const int wr = (rd == 2) ? 0 : rd + 1;
        float o[4];
        if (t < 256) {
            const float4 ghr = *(const float4*)&ghsT[i][j4];
            const float4 ghz = *(const float4*)&ghsT[i][32 + j4];
            const float4 ghn = *(const float4*)&ghsT[i][64 + j4];
            const float hrr[4] = {ghr.x, ghr.y, ghr.z, ghr.w};
            const float hzz[4] = {ghz.x, ghz.y, ghz.z, ghz.w};
            const float hnn[4] = {ghn.x, ghn.y, ghn.z, ghn.w};
            f16x4 hp;
            #pragma unroll
            for (int q = 0; q < 4; ++q) {
                const float hr = hrr[q] + bhr[q];
                const float hz = hzz[q] + bhz[q];
                const float hn = hnn[q] + bhn[q];
                const float h  = hv[q];
                const float rg = 1.f / (1.f + __expf(-((float)cr[q] + hr)));
                const float zg = 1.f / (1.f + __expf(-((float)cz[q] + hz)));
                const float ng = tanhf((float)cn[q] + rg * hn);
                const float ho = (1.f - zg) * ng + zg * h;
                const float hnew = (1.f - ca) * h + ca * ho;
                hv[q] = hnew;
                o[q] = hnew;
                hp[q] = (_Float16)hnew;
            }
            union { f16x4 v; unsigned long long u; } pk; pk.v = hp;
            _Float16* hd = hb + (size_t)wr * (BDIM * HDIM)
                         + (size_t)(g * 32 + i) * 512 + c * 32 + j4;
            asm volatile("global_store_dwordx2 %0, %1, off sc0 sc1"
                         :: "v"(hd), "v"(pk.u) : "memory");
            asm volatile("s_waitcnt vmcnt(0)" ::: "memory");
        }
        __syncthreads();
        if (t == 0) {
            unsigned int fv = (unsigned int)(s + 1);
            asm volatile("global_store_dword %0, %1, off sc0 sc1"
                         :: "v"(myflag), "v"(fv) : "memory");
        }
        // --- out store AFTER flag: off the critical path ---
        if (t < 256) {
            *(float4*)(out + ((size_t)(g * 32 + i) * LDIM + s) * HDIM + c * 32 + j4)
                = *(float4*)o;
        }
        cr = nr; cz = nz; cn = nn2; ca = na;
        rd = wr;
    }

    if (t < 256) {
        float o[4] = {hv[0], hv[1], hv[2], hv[3]};
        *(float4*)(hx + (size_t)(g * 32 + i) * 512 + c * 32 + j4) = *(float4*)o;
    }
}

// ---------------------------------------------------------------------------
extern "C" void kernel_launch(void* const* d_in, const int* in_sizes, int n_in,
                              void* d_out, int out_size, void* d_ws, size_t ws_size,
                              hipStream_t stream)
{
    const float* x   = (const float*)d_in[0];
    const float* att = (const float*)d_in[1];
    const float* h0  = (const float*)d_in[2];
    const float* wih = (const float*)d_in[3];
    const float* whh = (const float*)d_in[4];
    const float* bih = (const float*)d_in[5];
    const float* bhh = (const float*)d_in[6];

    float* out = (float*)d_out;
    float* hx  = out + (size_t)BDIM * LDIM * HDIM;

    // ws layout:
    //   wfA   @ 0x000000  (1.5MB fragment-packed weights; reused wfi->wfh)
    //   flags @ 0x180000  (256 u32)
    //   hb    @ 0x190000  (3 x 512KB f16 h exchange)
    //   gx    @ 0x310000  (~302MB f16)
    char* ws = (char*)d_ws;
    f16x8*        wfA   = (f16x8*)ws;
    unsigned int* flags = (unsigned int*)(ws + 0x180000);
    _Float16*     hb    = (_Float16*)(ws + 0x190000);
    _Float16*     gx    = (_Float16*)(ws + 0x310000);

    k_init<<<1024, 256, 0, stream>>>(flags, h0, hb);
    k_pack_wfi<<<384, 256, 0, stream>>>(wih, wfA);
    k_gemm_gx<<<4800, 256, 0, stream>>>(x, wfA, bih, gx);
    k_pack_wfh<<<384, 256, 0, stream>>>(whh, wfA);   // overwrites wfi (gemm done)
    k_recur<<<256, 384, 0, stream>>>(gx, att, h0, wfA, bhh, hb, flags, out, hx);
}

// Round 7
// 1358.875 us; speedup vs baseline: 12.4486x; 1.0010x over previous
//
#include <hip/hip_runtime.h>
#include <hip/hip_fp16.h>

#define LDIM 200
#define BDIM 512
#define IDIM 512
#define HDIM 512
#define GDIM 1536  // 3*H
#define NGRP 16    // batch groups (32 rows each)
#define NCOL 16    // col groups   (32 h-cols each)

typedef _Float16 f16x8 __attribute__((ext_vector_type(8)));
typedef _Float16 f16x4 __attribute__((ext_vector_type(4)));
typedef float    f32x4 __attribute__((ext_vector_type(4)));
typedef unsigned int u32x4 __attribute__((ext_vector_type(4)));

// ---------------------------------------------------------------------------
// k_init: seed hb2 buffer 0 with h0 payloads + seq=0.
// unit u (0..65535): row = u>>7, col4 = u&127 -> {f16x4(h0), 0, 0}
// ---------------------------------------------------------------------------
__global__ __launch_bounds__(256) void k_init(
    const float* __restrict__ h0, u32x4* __restrict__ hb2)
{
    int u = blockIdx.x * 256 + threadIdx.x;
    if (u >= BDIM * HDIM / 4) return;
    const int row = u >> 7, col4 = u & 127;
    const float4 v = *(const float4*)(h0 + (size_t)row * HDIM + col4 * 4);
    union { f16x4 h; unsigned int d[2]; } pk;
    pk.h[0] = (_Float16)v.x; pk.h[1] = (_Float16)v.y;
    pk.h[2] = (_Float16)v.z; pk.h[3] = (_Float16)v.w;
    u32x4 st; st[0] = pk.d[0]; st[1] = pk.d[1]; st[2] = 0u; st[3] = 0u;
    hb2[u] = st;
}

// ---------------------------------------------------------------------------
// k_pack_wfi: pack w_ih (f32 [1536][512]) into MFMA B-fragment order, f16.
// (round-3 verified)
// ---------------------------------------------------------------------------
__global__ __launch_bounds__(256) void k_pack_wfi(
    const float* __restrict__ w, f16x8* __restrict__ wf)
{
    int u = blockIdx.x * 256 + threadIdx.x;
    if (u >= (GDIM / 16) * 16 * 64) return;
    const int lane = u & 63;
    const int kk   = (u >> 6) & 15;
    const int ntg  = u >> 10;
    const int n = ntg * 16 + (lane & 15);
    const int k = kk * 32 + (lane >> 4) * 8;
    const float* src = w + (size_t)n * IDIM + k;
    f16x8 v;
    #pragma unroll
    for (int j = 0; j < 8; ++j) v[j] = (_Float16)src[j];
    wf[u] = v;
}

// ---------------------------------------------------------------------------
// k_pack_wfh: pack w_hh into per-colgroup fragment order. (round-3 verified)
// ---------------------------------------------------------------------------
__global__ __launch_bounds__(256) void k_pack_wfh(
    const float* __restrict__ w, f16x8* __restrict__ wf)
{
    int u = blockIdx.x * 256 + threadIdx.x;
    if (u >= NCOL * 6 * 16 * 64) return;
    const int lane = u & 63;
    const int kk   = (u >> 6) & 15;
    const int cw   = u >> 10;
    const int wv   = cw % 6;
    const int c    = cw / 6;
    const int n_local = wv * 16 + (lane & 15);
    const int gate    = n_local >> 5;
    const int j_local = n_local & 31;
    const int n = gate * 512 + c * 32 + j_local;
    const int k = kk * 32 + (lane >> 4) * 8;
    const float* src = w + (size_t)n * HDIM + k;
    f16x8 v;
    #pragma unroll
    for (int j = 0; j < 8; ++j) v[j] = (_Float16)src[j];
    wf[u] = v;
}

// ---------------------------------------------------------------------------
// K1 v2: gx = x @ w_ih^T + b_ih (f16 out). (round-6 verified)
// ---------------------------------------------------------------------------
__global__ __launch_bounds__(256, 2) void k_gemm_gx(
    const float* __restrict__ x, const f16x8* __restrict__ wfi,
    const float* __restrict__ bih, _Float16* __restrict__ gx)
{
    const int bid  = blockIdx.x;
    const int xcd  = bid & 7;
    const int slot = bid >> 3;          // 0..599
    const int gl   = slot / 3;          // 0..199
    const int ng   = slot % 3;          // 0..2
    const int m0   = (xcd * 200 + gl) * 64;
    const int n0   = ng * 512;

    const int t   = threadIdx.x;
    const int wid = t >> 6;             // n-quarter 0..3
    const int l   = t & 63;

    __shared__ __align__(16) _Float16 As[64 * 512];    // 64KB, XOR-swizzled

    {
        const int r  = t >> 2;
        const int k0 = (t & 3) * 128;
        const int m  = m0 + r;
        const float* src = x + ((size_t)(m & 511) * LDIM + (m >> 9)) * IDIM + k0;
        #pragma unroll
        for (int jj = 0; jj < 16; ++jj) {
            const float4 v0 = *(const float4*)(src + jj * 8);
            const float4 v1 = *(const float4*)(src + jj * 8 + 4);
            f16x8 hq;
            hq[0] = (_Float16)v0.x; hq[1] = (_Float16)v0.y;
            hq[2] = (_Float16)v0.z; hq[3] = (_Float16)v0.w;
            hq[4] = (_Float16)v1.x; hq[5] = (_Float16)v1.y;
            hq[6] = (_Float16)v1.z; hq[7] = (_Float16)v1.w;
            const int byte = (r * 1024 + (k0 + jj * 8) * 2) ^ ((r & 7) << 4);
            *(f16x8*)((char*)As + byte) = hq;
        }
    }
    __syncthreads();

    const f16x8* bp = wfi + (size_t)((ng * 4 + wid) * 8) * 1024 + l;
    const int kb8   = (l >> 4) * 16;
    const int rbase = l & 15;

    f32x4 acc[4][8] = {};

    for (int kk = 0; kk < 16; ++kk) {
        f16x8 a[4];
        #pragma unroll
        for (int mt = 0; mt < 4; ++mt) {
            const int r = mt * 16 + rbase;
            const int byte = (r * 1024 + kk * 64 + kb8) ^ ((r & 7) << 4);
            a[mt] = *(const f16x8*)((const char*)As + byte);
        }
        const f16x8* bk = bp + kk * 64;
        #pragma unroll
        for (int nt = 0; nt < 8; ++nt) {
            const f16x8 bf = bk[(size_t)nt * 1024];
            #pragma unroll
            for (int mt = 0; mt < 4; ++mt)
                acc[mt][nt] = __builtin_amdgcn_mfma_f32_16x16x32_f16(a[mt], bf, acc[mt][nt], 0, 0, 0);
        }
    }

    #pragma unroll
    for (int nt = 0; nt < 8; ++nt) {
        const int n = n0 + wid * 128 + nt * 16 + (l & 15);
        const float bv = bih[n];
        #pragma unroll
        for (int mt = 0; mt < 4; ++mt) {
            #pragma unroll
            for (int r = 0; r < 4; ++r) {
                const int m = m0 + mt * 16 + (l >> 4) * 4 + r;
                gx[(size_t)m * GDIM + n] = (_Float16)(acc[mt][nt][r] + bv);
            }
        }
    }
}

// ---------------------------------------------------------------------------
// K2: persistent recurrence. 256 blocks = 16 batch-groups x 16 col-groups,
// 384 threads. w_hh slice in registers. NEW exchange protocol: each 16B
// unit = {f16x4 h payload, seq, seq}; producer fires ONE dwordx4 sc0sc1
// store (no ack wait, no flag); consumers poll their own units until
// seq == s. One IF round-trip per step. 3-buffer rotation (skew<=1 proof).
// ---------------------------------------------------------------------------
__global__ __launch_bounds__(384) void k_recur(
    const _Float16* __restrict__ gx, const float* __restrict__ att,
    const float* __restrict__ h0, const f16x8* __restrict__ wfh,
    const float* __restrict__ bhh, char* __restrict__ hb2c,
    float* __restrict__ out, float* __restrict__ hx)
{
    const int bid = blockIdx.x;
    const int g = bid >> 4;
    const int c = bid & 15;
    const int t = threadIdx.x;
    const int w = t >> 6;                        // 0..5
    const int l = t & 63;

    __shared__ __align__(16) _Float16 h16[32 * 512];   // 32KB, XOR-swizzled
    __shared__ float ghsT[32][100];                    // gh slice [row][n]

    // --- B fragments: wave w holds its 16 kk-frags in registers forever ---
    f16x8 B[16];
    {
        const f16x8* p = wfh + (size_t)(c * 6 + w) * 1024 + l;
        #pragma unroll
        for (int kk = 0; kk < 16; ++kk) B[kk] = p[kk * 64];
    }

    // --- gate-phase mapping: thread t<256 owns row i, cols j4..j4+3 ---
    const int i  = t >> 3;
    const int j4 = (t & 7) * 4;

    float bhr[4], bhz[4], bhn[4], hv[4];
    if (t < 256) {
        const float4 r4 = *(const float4*)(bhh + c * 32 + j4);
        const float4 z4 = *(const float4*)(bhh + 512 + c * 32 + j4);
        const float4 n4 = *(const float4*)(bhh + 1024 + c * 32 + j4);
        bhr[0]=r4.x; bhr[1]=r4.y; bhr[2]=r4.z; bhr[3]=r4.w;
        bhz[0]=z4.x; bhz[1]=z4.y; bhz[2]=z4.z; bhz[3]=z4.w;
        bhn[0]=n4.x; bhn[1]=n4.y; bhn[2]=n4.z; bhn[3]=n4.w;
        const float4 h4 = *(const float4*)(h0 + (size_t)(g * 32 + i) * 512 + c * 32 + j4);
        hv[0]=h4.x; hv[1]=h4.y; hv[2]=h4.z; hv[3]=h4.w;
    }

    const int ib = (l >> 4) * 4;
    const int nl = w * 16 + (l & 15);
    const int k8 = (l >> 4) * 8;
    const int rr0 = l & 15;
    const int rr1 = rr0 + 16;

    // --- prologue: gate inputs for step 0 ---
    f16x4 cr = {}, cz = {}, cn = {};
    float ca = 0.f;
    if (t < 256) {
        const _Float16* gp = gx + ((size_t)(g * 32 + i)) * GDIM + c * 32 + j4;
        cr = *(const f16x4*)(gp);
        cz = *(const f16x4*)(gp + 512);
        cn = *(const f16x4*)(gp + 1024);
        ca = att[g * 32 + i];
    }

    int rd = 0;                                  // hb2 read buffer = s % 3
    for (int s = 0; s < LDIM; ++s) {
        // --- fused poll+load: wait until all 16 of my units carry seq==s ---
        u32x4 vv[16];
        if (t < 256) {
            const char* hbase = hb2c
                + ((size_t)rd * 65536 + (size_t)g * 4096 + t) * 16;
            bool again = true;
            while (again) {
                #pragma unroll
                for (int q = 0; q < 16; ++q)
                    asm volatile("global_load_dwordx4 %0, %1, off sc0 sc1"
                                 : "=v"(vv[q]) : "v"(hbase + (size_t)q * 4096));
                asm volatile("s_waitcnt vmcnt(0)" ::: "memory");
                again = false;
                #pragma unroll
                for (int q = 0; q < 16; ++q)
                    again |= (vv[q][2] != (unsigned)s);
            }
            __builtin_amdgcn_sched_barrier(0);
            #pragma unroll
            for (int q = 0; q < 16; ++q) {
                const int idx = q * 256 + t;     // u64 payload, row-major
                const int row = idx >> 7;        // 128 units per row
                const int c8  = idx & 127;
                const int byte = (row * 1024 + c8 * 8) ^ ((row & 7) << 4);
                union { unsigned int d[2]; unsigned long long u; } m;
                m.d[0] = vv[q][0]; m.d[1] = vv[q][1];
                *(unsigned long long*)((char*)h16 + byte) = m.u;
            }
        }

        // --- 1-step-ahead gate prefetch (hidden under MFMA + gates) ---
        f16x4 nr = {}, nz = {}, nn2 = {};
        float na = 0.f;
        if (t < 256) {
            const int sn = (s < LDIM - 1) ? s + 1 : s;
            const _Float16* gp = gx + ((size_t)sn * BDIM + g * 32 + i) * GDIM + c * 32 + j4;
            nr  = *(const f16x4*)(gp);
            nz  = *(const f16x4*)(gp + 512);
            nn2 = *(const f16x4*)(gp + 1024);
            na  = att[(size_t)sn * BDIM + g * 32 + i];
        }
        __syncthreads();

        // --- MFMA: gh over K=512, wave w -> ghsT cols w*16..+16 ---
        f32x4 acc0 = {0.f, 0.f, 0.f, 0.f};
        f32x4 acc1 = {0.f, 0.f, 0.f, 0.f};
        #pragma unroll
        for (int kk = 0; kk < 16; ++kk) {
            const int kb = kk * 64 + k8 * 2;
            const int b0 = (rr0 * 1024 + kb) ^ ((rr0 & 7) << 4);
            const int b1 = (rr1 * 1024 + kb) ^ ((rr1 & 7) << 4);
            const f16x8 a0 = *(const f16x8*)((const char*)h16 + b0);
            const f16x8 a1 = *(const f16x8*)((const char*)h16 + b1);
            acc0 = __builtin_amdgcn_mfma_f32_16x16x32_f16(a0, B[kk], acc0, 0, 0, 0);
            acc1 = __builtin_amdgcn_mfma_f32_16x16x32_f16(a1, B[kk], acc1, 0, 0, 0);
        }
        #pragma unroll
        for (int q = 0; q < 4; ++q) {
            ghsT[ib + q][nl]      = acc0[q];
            ghsT[16 + ib + q][nl] = acc1[q];
        }
        __syncthreads();

        // --- gates + h update; fire single data+seq store (no ack wait) ---
        const int wr = (rd == 2) ? 0 : rd + 1;
        if (t < 256) {
            const float4 ghr = *(const float4*)&ghsT[i][j4];
            const float4 ghz = *(const float4*)&ghsT[i][32 + j4];
            const float4 ghn = *(const float4*)&ghsT[i][64 + j4];
            const float hrr[4] = {ghr.x, ghr.y, ghr.z, ghr.w};
            const float hzz[4] = {ghz.x, ghz.y, ghz.z, ghz.w};
            const float hnn[4] = {ghn.x, ghn.y, ghn.z, ghn.w};
            float o[4];
            f16x4 hp;
            #pragma unroll
            for (int q = 0; q < 4; ++q) {
                const float hr = hrr[q] + bhr[q];
                const float hz = hzz[q] + bhz[q];
                const float hn = hnn[q] + bhn[q];
                const float h  = hv[q];
                const float rg = 1.f / (1.f + __expf(-((float)cr[q] + hr)));
                const float zg = 1.f / (1.f + __expf(-((float)cz[q] + hz)));
                const float ng = tanhf((float)cn[q] + rg * hn);
                const float ho = (1.f - zg) * ng + zg * h;
                const float hnew = (1.f - ca) * h + ca * ho;
                hv[q] = hnew;
                o[q] = hnew;
                hp[q] = (_Float16)hnew;
            }
            union { f16x4 v; unsigned int d[2]; } pk; pk.v = hp;
            u32x4 st;
            st[0] = pk.d[0]; st[1] = pk.d[1];
            st[2] = (unsigned)(s + 1); st[3] = (unsigned)(s + 1);
            char* hd = hb2c + ((size_t)wr * 65536
                     + (size_t)(g * 32 + i) * 128 + (size_t)c * 8 + (t & 7)) * 16;
            asm volatile("global_store_dwordx4 %0, %1, off sc0 sc1"
                         :: "v"(hd), "v"(st) : "memory");
            // out store after the exchange store: off the critical path
            *(float4*)(out + ((size_t)(g * 32 + i) * LDIM + s) * HDIM + c * 32 + j4)
                = *(float4*)o;
        }
        cr = nr; cz = nz; cn = nn2; ca = na;
        rd = wr;
        // no loop-end barrier needed: next-step LDS writes are fenced by the
        // post-stage __syncthreads; gates (waves 0-3) precede staging in
        // program order; waves 4-5 wait at the post-stage barrier.
    }

    if (t < 256) {
        float o[4] = {hv[0], hv[1], hv[2], hv[3]};
        *(float4*)(hx + (size_t)(g * 32 + i) * 512 + c * 32 + j4) = *(float4*)o;
    }
}

// ---------------------------------------------------------------------------
extern "C" void kernel_launch(void* const* d_in, const int* in_sizes, int n_in,
                              void* d_out, int out_size, void* d_ws, size_t ws_size,
                              hipStream_t stream)
{
    const float* x   = (const float*)d_in[0];
    const float* att = (const float*)d_in[1];
    const float* h0  = (const float*)d_in[2];
    const float* wih = (const float*)d_in[3];
    const float* whh = (const float*)d_in[4];
    const float* bih = (const float*)d_in[5];
    const float* bhh = (const float*)d_in[6];

    float* out = (float*)d_out;
    float* hx  = out + (size_t)BDIM * LDIM * HDIM;

    // ws layout:
    //   wfA @ 0x000000  (1.5MB fragment-packed weights; reused wfi->wfh)
    //   hb2 @ 0x180000  (3 x 1MB  {payload,seq} exchange units)
    //   gx  @ 0x480000  (~302MB f16)
    char* ws = (char*)d_ws;
    f16x8*    wfA = (f16x8*)ws;
    char*     hb2 = ws + 0x180000;
    _Float16* gx  = (_Float16*)(ws + 0x480000);

    k_init<<<256, 256, 0, stream>>>(h0, (u32x4*)hb2);
    k_pack_wfi<<<384, 256, 0, stream>>>(wih, wfA);
    k_gemm_gx<<<4800, 256, 0, stream>>>(x, wfA, bih, gx);
    k_pack_wfh<<<384, 256, 0, stream>>>(whh, wfA);   // overwrites wfi (gemm done)
    k_recur<<<256, 384, 0, stream>>>(gx, att, h0, wfA, bhh, hb2, out, hx);
}